// Round 1
// baseline (3313.655 us; speedup 1.0000x reference)
//
#include <hip/hip_runtime.h>
#include <math.h>

#define CDIM 512
#define NPIX 4096
#define BATCH 2
#define NGROUP 32
#define CPG 16
#define EPSV 1e-6f

// ---------------- GroupNorm ----------------
// One block per (b, group). Each group = CPG*NPIX = 65536 contiguous floats.
__global__ __launch_bounds__(1024)
void gn_kernel(const float* __restrict__ x, const float* __restrict__ gamma,
               const float* __restrict__ beta, float* __restrict__ h) {
  const int NE = CPG * NPIX;  // 65536
  int b = blockIdx.x >> 5;
  int g = blockIdx.x & 31;
  size_t base = ((size_t)b * CDIM + (size_t)g * CPG) * NPIX;
  const float4* xv = (const float4*)(x + base);
  float4* hv = (float4*)(h + base);
  int t = threadIdx.x;
  float s = 0.f, ss = 0.f;
  for (int i = t; i < NE / 4; i += 1024) {
    float4 v = xv[i];
    s += (v.x + v.y) + (v.z + v.w);
    ss += v.x * v.x + v.y * v.y + v.z * v.z + v.w * v.w;
  }
#pragma unroll
  for (int off = 32; off >= 1; off >>= 1) {
    s += __shfl_down(s, off);
    ss += __shfl_down(ss, off);
  }
  __shared__ float redS[16], redQ[16];
  int wid = t >> 6;
  if ((t & 63) == 0) { redS[wid] = s; redQ[wid] = ss; }
  __syncthreads();
  __shared__ float s_mu, s_rs;
  if (t == 0) {
    float S = 0.f, Q = 0.f;
    for (int w = 0; w < 16; ++w) { S += redS[w]; Q += redQ[w]; }
    float mu = S / NE;
    float var = Q / NE - mu * mu;
    s_mu = mu;
    s_rs = rsqrtf(var + EPSV);
  }
  __syncthreads();
  float mu = s_mu, rs = s_rs;
  for (int i = t; i < NE / 4; i += 1024) {
    int c = g * CPG + (i >> 10);          // (i*4)/NPIX
    float ga = gamma[c] * rs;
    float be = beta[c] - mu * ga;
    float4 v = xv[i];
    v.x = v.x * ga + be;
    v.y = v.y * ga + be;
    v.z = v.z * ga + be;
    v.w = v.w * ga + be;
    hv[i] = v;
  }
}

// ---------------- 1x1 conv == GEMM: dst[b,o,n] = sum_c W[o,c]*src[b,c,n]+bias[o] (+resid) ----------------
#define BM 64
#define BN 64
#define BK 16
#define WPAD 68  // +4 pad: breaks 16-way store conflict, keeps 16B row alignment (68*4=272=17*16)

__global__ __launch_bounds__(256)
void conv1x1_kernel(const float* __restrict__ W, const float* __restrict__ bias,
                    const float* __restrict__ src, const float* __restrict__ resid,
                    float* __restrict__ dst) {
  __shared__ __align__(16) float w_lds[BK][WPAD];  // [c][o]
  __shared__ __align__(16) float h_lds[BK][BN];    // [c][n]
  int t = threadIdx.x;
  int nBase = blockIdx.x * BN;
  int oBase = blockIdx.y * BM;
  int b = blockIdx.z;
  const float* srcb = src + (size_t)b * CDIM * NPIX;
  float acc[4][4] = {};
  int o0 = 4 * (t >> 4);
  int j0 = 4 * (t & 15);
  for (int c0 = 0; c0 < CDIM; c0 += BK) {
    __syncthreads();
#pragma unroll
    for (int kk = 0; kk < 4; ++kk) {  // W tile 64o x 16c, transposed store
      int idx = t + 256 * kk;
      int o_l = idx >> 4, c_l = idx & 15;
      w_lds[c_l][o_l] = W[(size_t)(oBase + o_l) * CDIM + c0 + c_l];
    }
#pragma unroll
    for (int kk = 0; kk < 4; ++kk) {  // H tile 16c x 64n
      int idx = t + 256 * kk;
      int c_l = idx >> 6, j = idx & 63;
      h_lds[c_l][j] = srcb[(size_t)(c0 + c_l) * NPIX + nBase + j];
    }
    __syncthreads();
#pragma unroll
    for (int kk = 0; kk < BK; ++kk) {
      float4 a = *(const float4*)&w_lds[kk][o0];
      float4 bv = *(const float4*)&h_lds[kk][j0];
      float av[4] = {a.x, a.y, a.z, a.w};
      float bb[4] = {bv.x, bv.y, bv.z, bv.w};
#pragma unroll
      for (int r = 0; r < 4; ++r)
#pragma unroll
        for (int s2 = 0; s2 < 4; ++s2) acc[r][s2] += av[r] * bb[s2];
    }
  }
#pragma unroll
  for (int r = 0; r < 4; ++r) {
    int o = oBase + o0 + r;
    float bi = bias[o];
    size_t off = ((size_t)b * CDIM + o) * NPIX + nBase + j0;
    float4 out;
    out.x = acc[r][0] + bi;
    out.y = acc[r][1] + bi;
    out.z = acc[r][2] + bi;
    out.w = acc[r][3] + bi;
    if (resid) {
      float4 rv = *(const float4*)(resid + off);
      out.x += rv.x; out.y += rv.y; out.z += rv.z; out.w += rv.w;
    }
    *(float4*)(dst + off) = out;
  }
}

// ---------------- Flash attention (fp32) ----------------
// Block: 256 thr (4 waves), QT=16 queries, loop key tiles of KT=64, C chunked by 64.
// S mapping : thread (wid,lane): rows i=4*wid+ir (ir 0..3), col j=lane.
// PV mapping: thread (wid,lane): rows i=4*wid+ir, channel cL=lane (+64*chunk).
// V stored rotated kv[c][(j+c)&63] so PV reads (lanes vary c, j fixed) are conflict-free.
#define QT 16
#define KT 64
#define CCH 64

__global__ __launch_bounds__(256)
void attn_kernel(const float* __restrict__ q, const float* __restrict__ k,
                 const float* __restrict__ v, float* __restrict__ ao) {
  __shared__ __align__(16) float qT[CDIM][QT];   // 32KB  [c][i]
  __shared__ __align__(16) float kv[CCH][KT];    // 16KB  K chunk, then V chunk (rotated)
  __shared__ __align__(16) float p_lds[QT][KT];  // 4KB
  int t = threadIdx.x;
  int lane = t & 63;
  int wid = t >> 6;
  int b = blockIdx.y;
  int iBase = blockIdx.x * QT;
  const float* qb = q + (size_t)b * CDIM * NPIX;
  const float* kb = k + (size_t)b * CDIM * NPIX;
  const float* vb = v + (size_t)b * CDIM * NPIX;

  for (int idx = t; idx < CDIM * QT; idx += 256) {
    int c = idx >> 4, i = idx & 15;
    qT[c][i] = qb[(size_t)c * NPIX + iBase + i];
  }

  float m[4], l[4], acc[8][4];
#pragma unroll
  for (int ir = 0; ir < 4; ++ir) { m[ir] = -1e30f; l[ir] = 0.f; }
#pragma unroll
  for (int ch = 0; ch < 8; ++ch)
#pragma unroll
    for (int ir = 0; ir < 4; ++ir) acc[ch][ir] = 0.f;

  const float scale = 0.044194173824159216f;  // 512^-0.5

  for (int jt = 0; jt < NPIX; jt += KT) {
    // ---- S = scale * Q^T K ----
    float s[4] = {0.f, 0.f, 0.f, 0.f};
    for (int ch = 0; ch < 8; ++ch) {
      __syncthreads();  // prev users of kv done
#pragma unroll
      for (int kk = 0; kk < 4; ++kk) {  // K chunk [64c][64j]
        int idx = t + 256 * kk;
        int cl = idx >> 4, j4 = idx & 15;
        *(float4*)&kv[cl][j4 * 4] =
            *(const float4*)&kb[(size_t)(ch * CCH + cl) * NPIX + jt + j4 * 4];
      }
      __syncthreads();
#pragma unroll 16
      for (int cc = 0; cc < CCH; ++cc) {
        float4 qv = *(const float4*)&qT[ch * CCH + cc][4 * wid];  // wave-uniform broadcast
        float kvv = kv[cc][lane];                                  // conflict-free
        s[0] += qv.x * kvv;
        s[1] += qv.y * kvv;
        s[2] += qv.z * kvv;
        s[3] += qv.w * kvv;
      }
    }
    // ---- online softmax (per-wave: row i's 64 j's live across the 64 lanes) ----
    float f[4];
#pragma unroll
    for (int ir = 0; ir < 4; ++ir) {
      float sv = s[ir] * scale;
      float mx = sv;
#pragma unroll
      for (int off = 1; off <= 32; off <<= 1) mx = fmaxf(mx, __shfl_xor(mx, off));
      float mn = fmaxf(m[ir], mx);
      float p = __expf(sv - mn);
      float rs = p;
#pragma unroll
      for (int off = 1; off <= 32; off <<= 1) rs += __shfl_xor(rs, off);
      f[ir] = __expf(m[ir] - mn);
      l[ir] = l[ir] * f[ir] + rs;
      m[ir] = mn;
      p_lds[4 * wid + ir][lane] = p;
    }
#pragma unroll
    for (int ch = 0; ch < 8; ++ch)
#pragma unroll
      for (int ir = 0; ir < 4; ++ir) acc[ch][ir] *= f[ir];
    // ---- PV: acc[i][c] += sum_j p[i][j] * v[c][j] ----
    for (int ch = 0; ch < 8; ++ch) {
      __syncthreads();  // S compute / prev PV done with kv; p_lds written
#pragma unroll
      for (int kk = 0; kk < 16; ++kk) {  // V chunk, rotated store
        int cl = 4 * kk + wid;
        kv[cl][(lane + cl) & 63] = vb[(size_t)(ch * CCH + cl) * NPIX + jt + lane];
      }
      __syncthreads();
#pragma unroll 4
      for (int j4 = 0; j4 < 16; ++j4) {
        float4 pv[4];
#pragma unroll
        for (int ir = 0; ir < 4; ++ir)
          pv[ir] = *(const float4*)&p_lds[4 * wid + ir][j4 * 4];  // broadcast
        float vv[4];
#pragma unroll
        for (int r = 0; r < 4; ++r)
          vv[r] = kv[lane][(j4 * 4 + r + lane) & 63];  // rotated: conflict-free
#pragma unroll
        for (int ir = 0; ir < 4; ++ir) {
          acc[ch][ir] += pv[ir].x * vv[0];
          acc[ch][ir] += pv[ir].y * vv[1];
          acc[ch][ir] += pv[ir].z * vv[2];
          acc[ch][ir] += pv[ir].w * vv[3];
        }
      }
    }
  }
  // write ao[b][c][iBase+i]
#pragma unroll
  for (int ch = 0; ch < 8; ++ch) {
    int c = ch * CCH + lane;
#pragma unroll
    for (int ir = 0; ir < 4; ++ir) {
      int i = 4 * wid + ir;
      ao[((size_t)b * CDIM + c) * NPIX + iBase + i] = acc[ch][ir] / l[ir];
    }
  }
}

extern "C" void kernel_launch(void* const* d_in, const int* in_sizes, int n_in,
                              void* d_out, int out_size, void* d_ws, size_t ws_size,
                              hipStream_t stream) {
  const float* x     = (const float*)d_in[0];
  const float* gamma = (const float*)d_in[1];
  const float* beta  = (const float*)d_in[2];
  const float* wq    = (const float*)d_in[3];
  const float* bq    = (const float*)d_in[4];
  const float* wk    = (const float*)d_in[5];
  const float* bk    = (const float*)d_in[6];
  const float* wv    = (const float*)d_in[7];
  const float* bv    = (const float*)d_in[8];
  const float* wp    = (const float*)d_in[9];
  const float* bp    = (const float*)d_in[10];
  float* out = (float*)d_out;

  size_t per = (size_t)BATCH * CDIM * NPIX;  // 4,194,304 floats
  float* h    = (float*)d_ws;                // 5 buffers * 16.8MB = 83.9MB of ws
  float* qbuf = h + per;
  float* kbuf = qbuf + per;
  float* vbuf = kbuf + per;
  float* ao   = vbuf + per;

  gn_kernel<<<dim3(BATCH * NGROUP), dim3(1024), 0, stream>>>(x, gamma, beta, h);
  dim3 cgrid(NPIX / BN, CDIM / BM, BATCH);
  conv1x1_kernel<<<cgrid, 256, 0, stream>>>(wq, bq, h, nullptr, qbuf);
  conv1x1_kernel<<<cgrid, 256, 0, stream>>>(wk, bk, h, nullptr, kbuf);
  conv1x1_kernel<<<cgrid, 256, 0, stream>>>(wv, bv, h, nullptr, vbuf);
  attn_kernel<<<dim3(NPIX / QT, BATCH), 256, 0, stream>>>(qbuf, kbuf, vbuf, ao);
  conv1x1_kernel<<<cgrid, 256, 0, stream>>>(wp, bp, ao, x, out);
}

// Round 2
// 808.276 us; speedup vs baseline: 4.0997x; 4.0997x over previous
//
#include <hip/hip_runtime.h>
#include <hip/hip_bf16.h>
#include <math.h>

#define CDIM 512
#define NPIX 4096
#define BATCH 2
#define NGROUP 32
#define CPG 16
#define EPSV 1e-6f

#define QT 64
#define KT 64
#define KSPLIT 2
#define KEYS_PER (NPIX / KSPLIT)
#define NKT (KEYS_PER / KT)

typedef __attribute__((ext_vector_type(4))) float f32x4;
typedef __attribute__((ext_vector_type(8))) short bf16x8;
typedef __attribute__((ext_vector_type(8))) unsigned short ushort8v;
typedef __attribute__((ext_vector_type(4))) unsigned short ushort4v;

__device__ inline unsigned short f2bf(float x) {
  __hip_bfloat16 h = __float2bfloat16(x);
  union { __hip_bfloat16 b; unsigned short u; } cv;
  cv.b = h;
  return cv.u;
}
__device__ inline float bf2f(unsigned short u) {
  union { __hip_bfloat16 b; unsigned short u; } cv;
  cv.u = u;
  return __bfloat162float(cv.b);
}

__device__ inline void gload_lds16(const void* g, void* l) {
  __builtin_amdgcn_global_load_lds((const __attribute__((address_space(1))) void*)g,
                                   (__attribute__((address_space(3))) void*)l, 16, 0, 0);
}

// ---------------- GroupNorm ----------------
__global__ __launch_bounds__(1024)
void gn_kernel(const float* __restrict__ x, const float* __restrict__ gamma,
               const float* __restrict__ beta, float* __restrict__ h) {
  const int NE = CPG * NPIX;
  int b = blockIdx.x >> 5;
  int g = blockIdx.x & 31;
  size_t base = ((size_t)b * CDIM + (size_t)g * CPG) * NPIX;
  const float4* xv = (const float4*)(x + base);
  float4* hv = (float4*)(h + base);
  int t = threadIdx.x;
  float s = 0.f, ss = 0.f;
  for (int i = t; i < NE / 4; i += 1024) {
    float4 v = xv[i];
    s += (v.x + v.y) + (v.z + v.w);
    ss += v.x * v.x + v.y * v.y + v.z * v.z + v.w * v.w;
  }
#pragma unroll
  for (int off = 32; off >= 1; off >>= 1) {
    s += __shfl_down(s, off);
    ss += __shfl_down(ss, off);
  }
  __shared__ float redS[16], redQ[16];
  int wid = t >> 6;
  if ((t & 63) == 0) { redS[wid] = s; redQ[wid] = ss; }
  __syncthreads();
  __shared__ float s_mu, s_rs;
  if (t == 0) {
    float S = 0.f, Q = 0.f;
    for (int w = 0; w < 16; ++w) { S += redS[w]; Q += redQ[w]; }
    float mu = S / NE;
    float var = Q / NE - mu * mu;
    s_mu = mu;
    s_rs = rsqrtf(var + EPSV);
  }
  __syncthreads();
  float mu = s_mu, rs = s_rs;
  for (int i = t; i < NE / 4; i += 1024) {
    int c = g * CPG + (i >> 10);
    float ga = gamma[c] * rs;
    float be = beta[c] - mu * ga;
    float4 v = xv[i];
    v.x = v.x * ga + be;
    v.y = v.y * ga + be;
    v.z = v.z * ga + be;
    v.w = v.w * ga + be;
    hv[i] = v;
  }
}

// ---------------- conv1x1 GEMM ----------------
// MODE 0: fp32 out + residual (proj). MODE 1: bf16 hi/lo TRANSPOSED out [b][n][c] (q,k).
// MODE 2: bf16 hi/lo out [b][c][n] (v).
#define BKc 16
#define WPAD 68

template <int MODE>
__global__ __launch_bounds__(256)
void conv1x1_kernel(const float* __restrict__ W, const float* __restrict__ bias,
                    const float* __restrict__ src, const float* __restrict__ resid,
                    float* __restrict__ dst, unsigned short* __restrict__ dsth,
                    unsigned short* __restrict__ dstl) {
  __shared__ __align__(16) float w_lds[BKc][WPAD];
  __shared__ __align__(16) float h_lds[BKc][64];
  __shared__ __align__(16) unsigned short t_lds[64][72];
  int t = threadIdx.x;
  int nBase = blockIdx.x * 64;
  int oBase = blockIdx.y * 64;
  int b = blockIdx.z;
  const float* srcb = src + (size_t)b * CDIM * NPIX;
  float acc[4][4] = {};
  int o0 = 4 * (t >> 4);
  int j0 = 4 * (t & 15);
  for (int c0 = 0; c0 < CDIM; c0 += BKc) {
    __syncthreads();
#pragma unroll
    for (int kk = 0; kk < 4; ++kk) {
      int idx = t + 256 * kk;
      int o_l = idx >> 4, c_l = idx & 15;
      w_lds[c_l][o_l] = W[(size_t)(oBase + o_l) * CDIM + c0 + c_l];
    }
#pragma unroll
    for (int kk = 0; kk < 4; ++kk) {
      int idx = t + 256 * kk;
      int c_l = idx >> 6, j = idx & 63;
      h_lds[c_l][j] = srcb[(size_t)(c0 + c_l) * NPIX + nBase + j];
    }
    __syncthreads();
#pragma unroll
    for (int kk = 0; kk < BKc; ++kk) {
      float4 a = *(const float4*)&w_lds[kk][o0];
      float4 bv = *(const float4*)&h_lds[kk][j0];
      float av[4] = {a.x, a.y, a.z, a.w};
      float bb[4] = {bv.x, bv.y, bv.z, bv.w};
#pragma unroll
      for (int r = 0; r < 4; ++r)
#pragma unroll
        for (int s2 = 0; s2 < 4; ++s2) acc[r][s2] += av[r] * bb[s2];
    }
  }
  // epilogue
  if (MODE == 0) {
#pragma unroll
    for (int r = 0; r < 4; ++r) {
      int o = oBase + o0 + r;
      float bi = bias[o];
      size_t off = ((size_t)b * CDIM + o) * NPIX + nBase + j0;
      float4 out;
      out.x = acc[r][0] + bi;
      out.y = acc[r][1] + bi;
      out.z = acc[r][2] + bi;
      out.w = acc[r][3] + bi;
      float4 rv = *(const float4*)(resid + off);
      out.x += rv.x; out.y += rv.y; out.z += rv.z; out.w += rv.w;
      *(float4*)(dst + off) = out;
    }
  } else if (MODE == 2) {
#pragma unroll
    for (int r = 0; r < 4; ++r) {
      int o = oBase + o0 + r;
      float bi = bias[o];
      size_t off = ((size_t)b * CDIM + o) * NPIX + nBase + j0;
      ushort4v hv, lv;
#pragma unroll
      for (int s2 = 0; s2 < 4; ++s2) {
        float val = acc[r][s2] + bi;
        unsigned short hu = f2bf(val);
        hv[s2] = hu;
        lv[s2] = f2bf(val - bf2f(hu));
      }
      *(ushort4v*)(dsth + off) = hv;
      *(ushort4v*)(dstl + off) = lv;
    }
  } else {
    // MODE 1: transpose via LDS, two phases (hi then lo)
    float biv[4];
#pragma unroll
    for (int r = 0; r < 4; ++r) biv[r] = bias[oBase + o0 + r];
#pragma unroll
    for (int phase = 0; phase < 2; ++phase) {
      __syncthreads();
#pragma unroll
      for (int r = 0; r < 4; ++r)
#pragma unroll
        for (int s2 = 0; s2 < 4; ++s2) {
          float val = acc[r][s2] + biv[r];
          unsigned short hu = f2bf(val);
          t_lds[j0 + s2][o0 + r] = phase == 0 ? hu : f2bf(val - bf2f(hu));
        }
      __syncthreads();
      unsigned short* dp = phase == 0 ? dsth : dstl;
      int row = t >> 2, seg = t & 3;
      size_t goff = ((size_t)b * NPIX + nBase + row) * CDIM + oBase + seg * 16;
#pragma unroll
      for (int e = 0; e < 2; ++e)
        *(ushort8v*)(dp + goff + 8 * e) = *(ushort8v*)&t_lds[row][seg * 16 + 8 * e];
    }
  }
}

// ---------------- MFMA flash attention ----------------
// 256 thr (4 waves). QT=64 rows/block, KT=64 keys/tile, keys split KSPLIT ways.
// S phase: row-split (wave w rows 16w..+15), QK^T 3-pass (QhKh + QlKh + QhKl).
// PV phase: chan-split (wave w chans 128w..+127), 2-pass (Phi*Vhi + Phi*Vlo).
// K staged in LDS via global_load_lds w/ pre-swizzled source; V/Q gathered from L2.
__global__ __launch_bounds__(256, 1)
void attn_kernel(const unsigned short* __restrict__ qt_hi, const unsigned short* __restrict__ qt_lo,
                 const unsigned short* __restrict__ kt_hi, const unsigned short* __restrict__ kt_lo,
                 const unsigned short* __restrict__ v_hi, const unsigned short* __restrict__ v_lo,
                 float* __restrict__ opart, float* __restrict__ mlbuf) {
  __shared__ __align__(16) unsigned short ktile[2][64 * 64];  // [hi/lo][key*64+slot], slot=cb^(key&7)
  __shared__ __align__(16) unsigned short plds[64 * 72];      // [row][key], +8 pad
  __shared__ float flds[64];

  int t = threadIdx.x;
  int lane = t & 63;
  int w = t >> 6;
  int qtile = blockIdx.x, b = blockIdx.y, ks = blockIdx.z;
  int qBase = qtile * QT;

  const unsigned short* qh = qt_hi + ((size_t)b * NPIX + qBase) * CDIM;
  const unsigned short* ql = qt_lo + ((size_t)b * NPIX + qBase) * CDIM;
  const unsigned short* kh = kt_hi + ((size_t)b * NPIX + ks * KEYS_PER) * CDIM;
  const unsigned short* kl = kt_lo + ((size_t)b * NPIX + ks * KEYS_PER) * CDIM;
  const unsigned short* vh = v_hi + (size_t)b * CDIM * NPIX + ks * KEYS_PER;
  const unsigned short* vl = v_lo + (size_t)b * CDIM * NPIX + ks * KEYS_PER;

  // Q-hi fragments in registers (row-split): lane row = 16w+(lane&15), k = 32cc+8*(lane>>4)
  const unsigned short* qrow_h = qh + (size_t)(16 * w + (lane & 15)) * CDIM + 8 * (lane >> 4);
  const unsigned short* qrow_l = ql + (size_t)(16 * w + (lane & 15)) * CDIM + 8 * (lane >> 4);
  bf16x8 qfh[16];
#pragma unroll
  for (int cc = 0; cc < 16; ++cc) qfh[cc] = *(const bf16x8*)(qrow_h + 32 * cc);

  f32x4 Oacc[4][8];
#pragma unroll
  for (int rg = 0; rg < 4; ++rg)
#pragma unroll
    for (int cf = 0; cf < 8; ++cf) Oacc[rg][cf] = (f32x4){0.f, 0.f, 0.f, 0.f};
  float mrow[4], lrow[4];
#pragma unroll
  for (int r = 0; r < 4; ++r) { mrow[r] = -1e30f; lrow[r] = 0.f; }

  const float scale = 0.044194173824159216f;

  for (int kt = 0; kt < NKT; ++kt) {
    // ---- S = Q K^T over 8 chunks of 64 chans ----
    f32x4 Sacc[4];
#pragma unroll
    for (int f = 0; f < 4; ++f) Sacc[f] = (f32x4){0.f, 0.f, 0.f, 0.f};
    for (int ch = 0; ch < 8; ++ch) {
      __syncthreads();
#pragma unroll
      for (int j = 0; j < 4; ++j) {
        int idx = w * 4 + j;
        int buf = idx >> 3;
        int sub = idx & 7;
        const unsigned short* src = buf ? kl : kh;
        int key = sub * 8 + (lane >> 3);
        int cb = (lane & 7) ^ ((lane >> 3) & 7);  // pre-swizzled source chan-block
        gload_lds16(src + (size_t)(kt * KT + key) * CDIM + ch * 64 + cb * 8,
                    &ktile[buf][sub * 512]);
      }
      __syncthreads();
#pragma unroll
      for (int sc = 0; sc < 2; ++sc) {
        int cc = ch * 2 + sc;
        bf16x8 qflo = *(const bf16x8*)(qrow_l + 32 * cc);
        int cbl = sc * 4 + (lane >> 4);
#pragma unroll
        for (int f = 0; f < 4; ++f) {
          int key = 16 * f + (lane & 15);
          int swz = cbl ^ (key & 7);
          bf16x8 bh = *(const bf16x8*)&ktile[0][key * 64 + swz * 8];
          bf16x8 bl = *(const bf16x8*)&ktile[1][key * 64 + swz * 8];
          Sacc[f] = __builtin_amdgcn_mfma_f32_16x16x32_bf16(qfh[cc], bh, Sacc[f], 0, 0, 0);
          Sacc[f] = __builtin_amdgcn_mfma_f32_16x16x32_bf16(qflo, bh, Sacc[f], 0, 0, 0);
          Sacc[f] = __builtin_amdgcn_mfma_f32_16x16x32_bf16(qfh[cc], bl, Sacc[f], 0, 0, 0);
        }
      }
    }
    // ---- online softmax (row-split; D-frag: col=lane&15=key, row=4*(lane>>4)+r) ----
    float fscale[4];
#pragma unroll
    for (int r = 0; r < 4; ++r) {
      float sv[4];
#pragma unroll
      for (int f = 0; f < 4; ++f) sv[f] = Sacc[f][r] * scale;
      float mx = fmaxf(fmaxf(sv[0], sv[1]), fmaxf(sv[2], sv[3]));
#pragma unroll
      for (int off = 1; off <= 8; off <<= 1) mx = fmaxf(mx, __shfl_xor(mx, off));
      float mn = fmaxf(mrow[r], mx);
      float rs = 0.f;
      int prow = 16 * w + 4 * (lane >> 4) + r;
#pragma unroll
      for (int f = 0; f < 4; ++f) {
        float p = __expf(sv[f] - mn);
        rs += p;
        plds[prow * 72 + 16 * f + (lane & 15)] = f2bf(p);
      }
#pragma unroll
      for (int off = 1; off <= 8; off <<= 1) rs += __shfl_xor(rs, off);
      fscale[r] = __expf(mrow[r] - mn);
      lrow[r] = lrow[r] * fscale[r] + rs;
      mrow[r] = mn;
      if ((lane & 15) == 0) flds[prow] = fscale[r];
    }
    __syncthreads();  // plds/flds ready for all waves
    // ---- O rescale + PV (chan-split) ----
#pragma unroll
    for (int rg = 0; rg < 4; ++rg) {
      float fr[4];
#pragma unroll
      for (int r = 0; r < 4; ++r) fr[r] = flds[16 * rg + 4 * (lane >> 4) + r];
#pragma unroll
      for (int cf = 0; cf < 8; ++cf)
#pragma unroll
        for (int r = 0; r < 4; ++r) Oacc[rg][cf][r] *= fr[r];
    }
#pragma unroll
    for (int kc = 0; kc < 2; ++kc) {
      bf16x8 ap[4];
#pragma unroll
      for (int rg = 0; rg < 4; ++rg)
        ap[rg] = *(const bf16x8*)&plds[(16 * rg + (lane & 15)) * 72 + 32 * kc + 8 * (lane >> 4)];
#pragma unroll
      for (int cf = 0; cf < 8; ++cf) {
        int chan = 128 * w + 16 * cf + (lane & 15);
        size_t vo = (size_t)chan * NPIX + kt * KT + 32 * kc + 8 * (lane >> 4);
        bf16x8 bvh = *(const bf16x8*)(vh + vo);
        bf16x8 bvl = *(const bf16x8*)(vl + vo);
#pragma unroll
        for (int rg = 0; rg < 4; ++rg) {
          Oacc[rg][cf] = __builtin_amdgcn_mfma_f32_16x16x32_bf16(ap[rg], bvh, Oacc[rg][cf], 0, 0, 0);
          Oacc[rg][cf] = __builtin_amdgcn_mfma_f32_16x16x32_bf16(ap[rg], bvl, Oacc[rg][cf], 0, 0, 0);
        }
      }
    }
  }
  // ---- epilogue: unnormalized O + (m,l) ----
  size_t obase = ((size_t)b * KSPLIT + ks) * CDIM * (size_t)NPIX;
#pragma unroll
  for (int rg = 0; rg < 4; ++rg)
#pragma unroll
    for (int cf = 0; cf < 8; ++cf) {
      int chan = 128 * w + 16 * cf + (lane & 15);
#pragma unroll
      for (int r = 0; r < 4; ++r) {
        int row = 16 * rg + 4 * (lane >> 4) + r;
        opart[obase + (size_t)chan * NPIX + qBase + row] = Oacc[rg][cf][r];
      }
    }
  if ((lane & 15) == 0) {
    size_t mlb = ((size_t)b * KSPLIT + ks) * NPIX;
#pragma unroll
    for (int r = 0; r < 4; ++r) {
      int row = 16 * w + 4 * (lane >> 4) + r;
      mlbuf[(mlb + qBase + row) * 2 + 0] = mrow[r];
      mlbuf[(mlb + qBase + row) * 2 + 1] = lrow[r];
    }
  }
}

// ---------------- combine (flash-decoding merge of KSPLIT partials) ----------------
__global__ __launch_bounds__(256)
void combine_kernel(const float* __restrict__ opart, const float* __restrict__ mlbuf,
                    float* __restrict__ ao) {
  size_t idx = (size_t)blockIdx.x * 256 + threadIdx.x;  // over B*CDIM*NPIX/4
  size_t e = idx * 4;
  int i = (int)(e & (NPIX - 1));
  size_t bc = e >> 12;           // b*CDIM + c
  int b = (int)(bc >> 9);
  size_t o0 = ((size_t)b * KSPLIT + 0) * CDIM * (size_t)NPIX + (bc & 511) * (size_t)NPIX + i - ((size_t)b * CDIM * NPIX - (size_t)b * CDIM * NPIX);
  // simpler: recompute directly
  size_t c = bc & 511;
  size_t base0 = (((size_t)b * KSPLIT + 0) * CDIM + c) * NPIX + i;
  size_t base1 = (((size_t)b * KSPLIT + 1) * CDIM + c) * NPIX + i;
  float4 v0 = *(const float4*)(opart + base0);
  float4 v1 = *(const float4*)(opart + base1);
  float4 out;
  size_t ml0 = ((size_t)b * KSPLIT + 0) * NPIX;
  size_t ml1 = ((size_t)b * KSPLIT + 1) * NPIX;
  float o0v[4] = {v0.x, v0.y, v0.z, v0.w};
  float o1v[4] = {v1.x, v1.y, v1.z, v1.w};
  float res[4];
#pragma unroll
  for (int k = 0; k < 4; ++k) {
    float m0 = mlbuf[(ml0 + i + k) * 2 + 0], l0 = mlbuf[(ml0 + i + k) * 2 + 1];
    float m1 = mlbuf[(ml1 + i + k) * 2 + 0], l1 = mlbuf[(ml1 + i + k) * 2 + 1];
    float M = fmaxf(m0, m1);
    float w0 = __expf(m0 - M), w1 = __expf(m1 - M);
    res[k] = (w0 * o0v[k] + w1 * o1v[k]) / (w0 * l0 + w1 * l1);
  }
  out.x = res[0]; out.y = res[1]; out.z = res[2]; out.w = res[3];
  *(float4*)(ao + (bc * NPIX) + i) = out;
}

extern "C" void kernel_launch(void* const* d_in, const int* in_sizes, int n_in,
                              void* d_out, int out_size, void* d_ws, size_t ws_size,
                              hipStream_t stream) {
  const float* x     = (const float*)d_in[0];
  const float* gamma = (const float*)d_in[1];
  const float* beta  = (const float*)d_in[2];
  const float* wq    = (const float*)d_in[3];
  const float* bq    = (const float*)d_in[4];
  const float* wk    = (const float*)d_in[5];
  const float* bk    = (const float*)d_in[6];
  const float* wv    = (const float*)d_in[7];
  const float* bv    = (const float*)d_in[8];
  const float* wp    = (const float*)d_in[9];
  const float* bp    = (const float*)d_in[10];
  float* out = (float*)d_out;

  const size_t per = (size_t)BATCH * CDIM * NPIX;  // 4,194,304
  char* ws = (char*)d_ws;
  // [0, 2*per*4): opart (first per*4 bytes double as h during phase 1)
  float* opart = (float*)ws;
  float* h = (float*)ws;
  unsigned short* qt_hi = (unsigned short*)(ws + 2 * per * 4);
  unsigned short* qt_lo = qt_hi + per;
  unsigned short* kt_hi = qt_lo + per;
  unsigned short* kt_lo = kt_hi + per;
  unsigned short* v_hi  = kt_lo + per;
  unsigned short* v_lo  = v_hi + per;
  float* ao = (float*)qt_hi;                       // aliases qt_hi+qt_lo (dead after attn)
  float* mlbuf = (float*)(ws + 2 * per * 4 + 6 * per * 2);

  gn_kernel<<<dim3(BATCH * NGROUP), dim3(1024), 0, stream>>>(x, gamma, beta, h);
  dim3 cgrid(NPIX / 64, CDIM / 64, BATCH);
  conv1x1_kernel<1><<<cgrid, 256, 0, stream>>>(wq, bq, h, nullptr, nullptr, qt_hi, qt_lo);
  conv1x1_kernel<1><<<cgrid, 256, 0, stream>>>(wk, bk, h, nullptr, nullptr, kt_hi, kt_lo);
  conv1x1_kernel<2><<<cgrid, 256, 0, stream>>>(wv, bv, h, nullptr, nullptr, v_hi, v_lo);
  attn_kernel<<<dim3(NPIX / QT, BATCH, KSPLIT), 256, 0, stream>>>(qt_hi, qt_lo, kt_hi, kt_lo,
                                                                  v_hi, v_lo, opart, mlbuf);
  combine_kernel<<<dim3((unsigned)(per / 4 / 256)), 256, 0, stream>>>(opart, mlbuf, ao);
  conv1x1_kernel<0><<<cgrid, 256, 0, stream>>>(wp, bp, ao, x, out, nullptr, nullptr);
}

// Round 3
// 763.796 us; speedup vs baseline: 4.3384x; 1.0582x over previous
//
#include <hip/hip_runtime.h>
#include <hip/hip_bf16.h>
#include <math.h>

#define CDIM 512
#define NPIX 4096
#define BATCH 2
#define NGROUP 32
#define CPG 16
#define EPSV 1e-6f

#define QT 64
#define KT 64

typedef __attribute__((ext_vector_type(4))) float f32x4;
typedef __attribute__((ext_vector_type(8))) short bf16x8;
typedef __attribute__((ext_vector_type(8))) unsigned short ushort8v;
typedef __attribute__((ext_vector_type(4))) unsigned short ushort4v;

__device__ inline unsigned short f2bf(float x) {
  union { __hip_bfloat16 b; unsigned short u; } cv;
  cv.b = __float2bfloat16(x);
  return cv.u;
}
__device__ inline float bf2f(unsigned short u) {
  union { __hip_bfloat16 b; unsigned short u; } cv;
  cv.u = u;
  return __bfloat162float(cv.b);
}

__device__ inline void gload_lds16(const void* g, void* l) {
  __builtin_amdgcn_global_load_lds((const __attribute__((address_space(1))) void*)g,
                                   (__attribute__((address_space(3))) void*)l, 16, 0, 0);
}

// ---------------- GroupNorm ----------------
__global__ __launch_bounds__(1024)
void gn_kernel(const float* __restrict__ x, const float* __restrict__ gamma,
               const float* __restrict__ beta, float* __restrict__ h) {
  const int NE = CPG * NPIX;
  int b = blockIdx.x >> 5;
  int g = blockIdx.x & 31;
  size_t base = ((size_t)b * CDIM + (size_t)g * CPG) * NPIX;
  const float4* xv = (const float4*)(x + base);
  float4* hv = (float4*)(h + base);
  int t = threadIdx.x;
  float s = 0.f, ss = 0.f;
  for (int i = t; i < NE / 4; i += 1024) {
    float4 v = xv[i];
    s += (v.x + v.y) + (v.z + v.w);
    ss += v.x * v.x + v.y * v.y + v.z * v.z + v.w * v.w;
  }
#pragma unroll
  for (int off = 32; off >= 1; off >>= 1) {
    s += __shfl_down(s, off);
    ss += __shfl_down(ss, off);
  }
  __shared__ float redS[16], redQ[16];
  int wid = t >> 6;
  if ((t & 63) == 0) { redS[wid] = s; redQ[wid] = ss; }
  __syncthreads();
  __shared__ float s_mu, s_rs;
  if (t == 0) {
    float S = 0.f, Q = 0.f;
    for (int w = 0; w < 16; ++w) { S += redS[w]; Q += redQ[w]; }
    float mu = S / NE;
    float var = Q / NE - mu * mu;
    s_mu = mu;
    s_rs = rsqrtf(var + EPSV);
  }
  __syncthreads();
  float mu = s_mu, rs = s_rs;
  for (int i = t; i < NE / 4; i += 1024) {
    int c = g * CPG + (i >> 10);
    float ga = gamma[c] * rs;
    float be = beta[c] - mu * ga;
    float4 v = xv[i];
    v.x = v.x * ga + be;
    v.y = v.y * ga + be;
    v.z = v.z * ga + be;
    v.w = v.w * ga + be;
    hv[i] = v;
  }
}

// ---------------- conv1x1 GEMM ----------------
// MODE 0: fp32 out + residual (proj). MODE 1: bf16 hi/lo TRANSPOSED out [b][n][c] (q,k).
// MODE 2: bf16 hi/lo out [b][c][n] (v).
#define BKc 16
#define WPAD 68

template <int MODE>
__global__ __launch_bounds__(256)
void conv1x1_kernel(const float* __restrict__ W, const float* __restrict__ bias,
                    const float* __restrict__ src, const float* __restrict__ resid,
                    float* __restrict__ dst, unsigned short* __restrict__ dsth,
                    unsigned short* __restrict__ dstl) {
  __shared__ __align__(16) float w_lds[BKc][WPAD];
  __shared__ __align__(16) float h_lds[BKc][64];
  __shared__ __align__(16) unsigned short t_lds[64][72];
  int t = threadIdx.x;
  int nBase = blockIdx.x * 64;
  int oBase = blockIdx.y * 64;
  int b = blockIdx.z;
  const float* srcb = src + (size_t)b * CDIM * NPIX;
  float acc[4][4] = {};
  int o0 = 4 * (t >> 4);
  int j0 = 4 * (t & 15);
  for (int c0 = 0; c0 < CDIM; c0 += BKc) {
    __syncthreads();
#pragma unroll
    for (int kk = 0; kk < 4; ++kk) {
      int idx = t + 256 * kk;
      int o_l = idx >> 4, c_l = idx & 15;
      w_lds[c_l][o_l] = W[(size_t)(oBase + o_l) * CDIM + c0 + c_l];
    }
#pragma unroll
    for (int kk = 0; kk < 4; ++kk) {
      int idx = t + 256 * kk;
      int c_l = idx >> 6, j = idx & 63;
      h_lds[c_l][j] = srcb[(size_t)(c0 + c_l) * NPIX + nBase + j];
    }
    __syncthreads();
#pragma unroll
    for (int kk = 0; kk < BKc; ++kk) {
      float4 a = *(const float4*)&w_lds[kk][o0];
      float4 bv = *(const float4*)&h_lds[kk][j0];
      float av[4] = {a.x, a.y, a.z, a.w};
      float bb[4] = {bv.x, bv.y, bv.z, bv.w};
#pragma unroll
      for (int r = 0; r < 4; ++r)
#pragma unroll
        for (int s2 = 0; s2 < 4; ++s2) acc[r][s2] += av[r] * bb[s2];
    }
  }
  if (MODE == 0) {
#pragma unroll
    for (int r = 0; r < 4; ++r) {
      int o = oBase + o0 + r;
      float bi = bias[o];
      size_t off = ((size_t)b * CDIM + o) * NPIX + nBase + j0;
      float4 out;
      out.x = acc[r][0] + bi;
      out.y = acc[r][1] + bi;
      out.z = acc[r][2] + bi;
      out.w = acc[r][3] + bi;
      float4 rv = *(const float4*)(resid + off);
      out.x += rv.x; out.y += rv.y; out.z += rv.z; out.w += rv.w;
      *(float4*)(dst + off) = out;
    }
  } else if (MODE == 2) {
#pragma unroll
    for (int r = 0; r < 4; ++r) {
      int o = oBase + o0 + r;
      float bi = bias[o];
      size_t off = ((size_t)b * CDIM + o) * NPIX + nBase + j0;
      ushort4v hv, lv;
#pragma unroll
      for (int s2 = 0; s2 < 4; ++s2) {
        float val = acc[r][s2] + bi;
        unsigned short hu = f2bf(val);
        hv[s2] = hu;
        lv[s2] = f2bf(val - bf2f(hu));
      }
      *(ushort4v*)(dsth + off) = hv;
      *(ushort4v*)(dstl + off) = lv;
    }
  } else {
    float biv[4];
#pragma unroll
    for (int r = 0; r < 4; ++r) biv[r] = bias[oBase + o0 + r];
#pragma unroll
    for (int phase = 0; phase < 2; ++phase) {
      __syncthreads();
#pragma unroll
      for (int r = 0; r < 4; ++r)
#pragma unroll
        for (int s2 = 0; s2 < 4; ++s2) {
          float val = acc[r][s2] + biv[r];
          unsigned short hu = f2bf(val);
          t_lds[j0 + s2][o0 + r] = phase == 0 ? hu : f2bf(val - bf2f(hu));
        }
      __syncthreads();
      unsigned short* dp = phase == 0 ? dsth : dstl;
      int row = t >> 2, seg = t & 3;
      size_t goff = ((size_t)b * NPIX + nBase + row) * CDIM + oBase + seg * 16;
#pragma unroll
      for (int e = 0; e < 2; ++e)
        *(ushort8v*)(dp + goff + 8 * e) = *(ushort8v*)&t_lds[row][seg * 16 + 8 * e];
    }
  }
}

// ---------------- MFMA flash attention ----------------
// 256 thr (4 waves). QT=64 rows/block, KT=64 keys/tile, keys split KS ways.
// S: 3-pass hi/lo QK^T, K staged in LDS (double-buffered chunks, counted vmcnt,
// raw barriers so prefetch survives). PV: chan-split, V register-direct, 2-pass.
// Epilogue: coalesced [row][chan] partial stores + (m,l); merged by combine_kernel.
template <int KS>
__global__ __launch_bounds__(256, 2)
void attn_kernel(const unsigned short* __restrict__ qt_hi, const unsigned short* __restrict__ qt_lo,
                 const unsigned short* __restrict__ kt_hi, const unsigned short* __restrict__ kt_lo,
                 const unsigned short* __restrict__ v_hi, const unsigned short* __restrict__ v_lo,
                 float* __restrict__ opart, float* __restrict__ mlbuf) {
  const int KEYS_PER = NPIX / KS;
  const int NKT = KEYS_PER / KT;
  __shared__ __align__(16) unsigned short ktile[2][2][64 * 64];  // [dbuf][hi/lo][key*64+slot]
  __shared__ __align__(16) unsigned short plds[64 * 72];
  __shared__ float flds[64];

  int t = threadIdx.x;
  int lane = t & 63;
  int l15 = lane & 15;
  int hh = lane >> 4;
  int w = t >> 6;
  int bid = blockIdx.x;
  int qtile, b, ks;
  if (KS == 4) {  // XCD swizzle: dispatch id % 8 -> XCD; give each XCD one (b,ks) panel
    int g = bid & 7;
    b = g & 1;
    ks = g >> 1;
    qtile = bid >> 3;
  } else {
    qtile = bid & 63;
    b = (bid >> 6) & 1;
    ks = bid >> 7;
  }
  int qBase = qtile * QT;

  const unsigned short* qh = qt_hi + ((size_t)b * NPIX + qBase) * CDIM;
  const unsigned short* ql = qt_lo + ((size_t)b * NPIX + qBase) * CDIM;
  const unsigned short* kh = kt_hi + ((size_t)b * NPIX + ks * KEYS_PER) * CDIM;
  const unsigned short* kl = kt_lo + ((size_t)b * NPIX + ks * KEYS_PER) * CDIM;
  const unsigned short* vh = v_hi + (size_t)b * CDIM * NPIX + ks * KEYS_PER;
  const unsigned short* vl = v_lo + (size_t)b * CDIM * NPIX + ks * KEYS_PER;

  // row-split S: lane's Q row = 16w + l15, k-slice = 32cc + 8*hh
  const unsigned short* qrow_h = qh + (size_t)(16 * w + l15) * CDIM + 8 * hh;
  const unsigned short* qrow_l = ql + (size_t)(16 * w + l15) * CDIM + 8 * hh;

  f32x4 Oacc[4][8];
#pragma unroll
  for (int rg = 0; rg < 4; ++rg)
#pragma unroll
    for (int cf = 0; cf < 8; ++cf) Oacc[rg][cf] = (f32x4){0.f, 0.f, 0.f, 0.f};
  float mrow[4], lrow[4];
#pragma unroll
  for (int r = 0; r < 4; ++r) { mrow[r] = -1e30f; lrow[r] = 0.f; }

  const float scale = 0.044194173824159216f;

  // issue one K chunk (64 keys x 64 chans, hi+lo) into dbuf d; 4 gload_lds per thread
  auto issue = [&](int ch, int d, int ktof) {
#pragma unroll
    for (int j = 0; j < 4; ++j) {
      int idx = w * 4 + j;
      int hl = idx >> 3;
      int sub = idx & 7;
      const unsigned short* src = hl ? kl : kh;
      int key = sub * 8 + (lane >> 3);
      int cb = (lane & 7) ^ ((lane >> 3) & 7);  // pre-swizzled source chan-block
      gload_lds16(src + (size_t)(ktof + key) * CDIM + ch * 64 + cb * 8,
                  &ktile[d][hl][sub * 512]);
    }
  };

  issue(0, 0, 0);  // prologue: kt=0 chunk0 -> buf0

  for (int kt = 0; kt < NKT; ++kt) {
    int ktof = kt * KT;
    // ---- S = Q K^T, 8 chunks of 64 chans, double-buffered ----
    f32x4 Sacc[4];
#pragma unroll
    for (int f = 0; f < 4; ++f) Sacc[f] = (f32x4){0.f, 0.f, 0.f, 0.f};
    for (int ch = 0; ch < 8; ++ch) {
      int d = ch & 1;
      if (ch < 7) {
        issue(ch + 1, (ch + 1) & 1, ktof);
        asm volatile("s_waitcnt vmcnt(4)" ::: "memory");  // chunk ch landed (newest-4 safe)
      } else {
        asm volatile("s_waitcnt vmcnt(0)" ::: "memory");
      }
      __builtin_amdgcn_s_barrier();
#pragma unroll
      for (int sc = 0; sc < 2; ++sc) {
        int cc = ch * 2 + sc;
        bf16x8 qfh_ = *(const bf16x8*)(qrow_h + 32 * cc);
        bf16x8 qfl_ = *(const bf16x8*)(qrow_l + 32 * cc);
        int cbl = sc * 4 + hh;
#pragma unroll
        for (int f = 0; f < 4; ++f) {
          int key = 16 * f + l15;
          int swz = cbl ^ (key & 7);
          bf16x8 bh = *(const bf16x8*)&ktile[d][0][key * 64 + swz * 8];
          bf16x8 bl = *(const bf16x8*)&ktile[d][1][key * 64 + swz * 8];
          Sacc[f] = __builtin_amdgcn_mfma_f32_16x16x32_bf16(qfh_, bh, Sacc[f], 0, 0, 0);
          Sacc[f] = __builtin_amdgcn_mfma_f32_16x16x32_bf16(qfl_, bh, Sacc[f], 0, 0, 0);
          Sacc[f] = __builtin_amdgcn_mfma_f32_16x16x32_bf16(qfh_, bl, Sacc[f], 0, 0, 0);
        }
      }
      __builtin_amdgcn_s_barrier();  // frees ktile[d]
    }
    // ---- prefetch next kt's chunk0 (covered by softmax+PV) ----
    if (kt + 1 < NKT) issue(0, 0, ktof + KT);
    // ---- online softmax (rows 16w..16w+15 of this wave) ----
#pragma unroll
    for (int r = 0; r < 4; ++r) {
      float sv[4];
#pragma unroll
      for (int f = 0; f < 4; ++f) sv[f] = Sacc[f][r] * scale;
      float mx = fmaxf(fmaxf(sv[0], sv[1]), fmaxf(sv[2], sv[3]));
#pragma unroll
      for (int off = 1; off <= 8; off <<= 1) mx = fmaxf(mx, __shfl_xor(mx, off));
      float mn = fmaxf(mrow[r], mx);
      float rs = 0.f;
      int prow = 16 * w + 4 * hh + r;
#pragma unroll
      for (int f = 0; f < 4; ++f) {
        float p = __expf(sv[f] - mn);
        rs += p;
        plds[prow * 72 + 16 * f + l15] = f2bf(p);
      }
#pragma unroll
      for (int off = 1; off <= 8; off <<= 1) rs += __shfl_xor(rs, off);
      float fs = __expf(mrow[r] - mn);
      lrow[r] = lrow[r] * fs + rs;
      mrow[r] = mn;
      if (l15 == 0) flds[prow] = fs;
    }
    asm volatile("s_waitcnt lgkmcnt(0)" ::: "memory");  // plds/flds visible
    __builtin_amdgcn_s_barrier();
    // ---- O rescale + PV (chan-split: wave w owns chans 128w..+127) ----
#pragma unroll
    for (int rg = 0; rg < 4; ++rg) {
      float fr[4];
#pragma unroll
      for (int r = 0; r < 4; ++r) fr[r] = flds[16 * rg + 4 * hh + r];
#pragma unroll
      for (int cf = 0; cf < 8; ++cf)
#pragma unroll
        for (int r = 0; r < 4; ++r) Oacc[rg][cf][r] *= fr[r];
    }
#pragma unroll
    for (int kc = 0; kc < 2; ++kc) {
      bf16x8 ap[4];
#pragma unroll
      for (int rg = 0; rg < 4; ++rg)
        ap[rg] = *(const bf16x8*)&plds[(16 * rg + l15) * 72 + 32 * kc + 8 * hh];
#pragma unroll
      for (int cf = 0; cf < 8; ++cf) {
        int chan = 128 * w + 16 * cf + l15;
        size_t vo = (size_t)chan * NPIX + ktof + 32 * kc + 8 * hh;
        bf16x8 bvh = *(const bf16x8*)(vh + vo);
        bf16x8 bvl = *(const bf16x8*)(vl + vo);
#pragma unroll
        for (int rg = 0; rg < 4; ++rg) {
          Oacc[rg][cf] = __builtin_amdgcn_mfma_f32_16x16x32_bf16(ap[rg], bvh, Oacc[rg][cf], 0, 0, 0);
          Oacc[rg][cf] = __builtin_amdgcn_mfma_f32_16x16x32_bf16(ap[rg], bvl, Oacc[rg][cf], 0, 0, 0);
        }
      }
    }
    // no trailing barrier needed: 16 barriers of next S-loop separate plds reads from writes
  }
  // ---- epilogue: coalesced [row][chan] partial + (m,l) ----
  size_t obase = (size_t)(b * KS + ks) * NPIX * CDIM;
#pragma unroll
  for (int rg = 0; rg < 4; ++rg)
#pragma unroll
    for (int cf = 0; cf < 8; ++cf) {
      int chan = 128 * w + 16 * cf + l15;
#pragma unroll
      for (int r = 0; r < 4; ++r) {
        int row = 16 * rg + 4 * hh + r;
        opart[obase + (size_t)(qBase + row) * CDIM + chan] = Oacc[rg][cf][r];
      }
    }
  if (l15 == 0) {
    size_t mlb = (size_t)(b * KS + ks) * NPIX;
#pragma unroll
    for (int r = 0; r < 4; ++r) {
      int row = 16 * w + 4 * hh + r;
      mlbuf[(mlb + qBase + row) * 2 + 0] = mrow[r];
      mlbuf[(mlb + qBase + row) * 2 + 1] = lrow[r];
    }
  }
}

// ---------------- combine: merge KS partials + transpose to [chan][pix] ----------------
template <int KS>
__global__ __launch_bounds__(256)
void combine_kernel(const float* __restrict__ opart, const float* __restrict__ mlbuf,
                    float* __restrict__ ao) {
  __shared__ float tl[64][67];
  __shared__ float wn[KS][64];
  int t = threadIdx.x;
  int r0 = blockIdx.x * 64, c0 = blockIdx.y * 64, b = blockIdx.z;
  if (t < 64) {
    int row = r0 + t;
    float m[KS], l[KS], M = -1e30f;
#pragma unroll
    for (int ks = 0; ks < KS; ++ks) {
      m[ks] = mlbuf[((size_t)(b * KS + ks) * NPIX + row) * 2 + 0];
      l[ks] = mlbuf[((size_t)(b * KS + ks) * NPIX + row) * 2 + 1];
      M = fmaxf(M, m[ks]);
    }
    float den = 0.f;
#pragma unroll
    for (int ks = 0; ks < KS; ++ks) den += __expf(m[ks] - M) * l[ks];
    float rden = 1.f / den;
#pragma unroll
    for (int ks = 0; ks < KS; ++ks) wn[ks][t] = __expf(m[ks] - M) * rden;
  }
  __syncthreads();
  int rr = t >> 4;
  int cc = (t & 15) * 4;
#pragma unroll
  for (int p = 0; p < 4; ++p) {
    int row = rr + 16 * p;
    float ax = 0.f, ay = 0.f, az = 0.f, aw = 0.f;
#pragma unroll
    for (int ks = 0; ks < KS; ++ks) {
      const float* src = opart + ((size_t)(b * KS + ks) * NPIX + r0 + row) * CDIM + c0 + cc;
      float4 v = *(const float4*)src;
      float wv = wn[ks][row];
      ax += wv * v.x; ay += wv * v.y; az += wv * v.z; aw += wv * v.w;
    }
    tl[row][cc + 0] = ax; tl[row][cc + 1] = ay; tl[row][cc + 2] = az; tl[row][cc + 3] = aw;
  }
  __syncthreads();
  int ch2 = t >> 4;
  int rw = (t & 15) * 4;
#pragma unroll
  for (int p = 0; p < 4; ++p) {
    int chn = ch2 + 16 * p;
    float4 o;
    o.x = tl[rw + 0][chn]; o.y = tl[rw + 1][chn]; o.z = tl[rw + 2][chn]; o.w = tl[rw + 3][chn];
    *(float4*)(ao + ((size_t)b * CDIM + c0 + chn) * NPIX + r0 + rw) = o;
  }
}

extern "C" void kernel_launch(void* const* d_in, const int* in_sizes, int n_in,
                              void* d_out, int out_size, void* d_ws, size_t ws_size,
                              hipStream_t stream) {
  const float* x     = (const float*)d_in[0];
  const float* gamma = (const float*)d_in[1];
  const float* beta  = (const float*)d_in[2];
  const float* wq    = (const float*)d_in[3];
  const float* bq    = (const float*)d_in[4];
  const float* wk    = (const float*)d_in[5];
  const float* bk    = (const float*)d_in[6];
  const float* wv    = (const float*)d_in[7];
  const float* bv    = (const float*)d_in[8];
  const float* wp    = (const float*)d_in[9];
  const float* bp    = (const float*)d_in[10];
  float* out = (float*)d_out;

  const size_t per = (size_t)BATCH * CDIM * NPIX;  // 4,194,304
  size_t need4 = 4 * per * 4 + 6 * per * 2 + (size_t)4 * BATCH * NPIX * 2 * 4;
  const int KS = (ws_size >= need4) ? 4 : 2;

  char* ws = (char*)d_ws;
  float* opart = (float*)ws;   // KS * per floats (first per*4 bytes double as h)
  float* h = (float*)ws;
  unsigned short* qt_hi = (unsigned short*)(ws + (size_t)KS * per * 4);
  unsigned short* qt_lo = qt_hi + per;
  unsigned short* kt_hi = qt_lo + per;
  unsigned short* kt_lo = kt_hi + per;
  unsigned short* v_hi  = kt_lo + per;
  unsigned short* v_lo  = v_hi + per;
  float* mlbuf = (float*)(ws + (size_t)KS * per * 4 + 6 * per * 2);
  float* ao = (float*)qt_hi;  // q hi+lo dead after attn; 16.8MB fits

  gn_kernel<<<dim3(BATCH * NGROUP), dim3(1024), 0, stream>>>(x, gamma, beta, h);
  dim3 cgrid(NPIX / 64, CDIM / 64, BATCH);
  conv1x1_kernel<1><<<cgrid, 256, 0, stream>>>(wq, bq, h, nullptr, nullptr, qt_hi, qt_lo);
  conv1x1_kernel<1><<<cgrid, 256, 0, stream>>>(wk, bk, h, nullptr, nullptr, kt_hi, kt_lo);
  conv1x1_kernel<2><<<cgrid, 256, 0, stream>>>(wv, bv, h, nullptr, nullptr, v_hi, v_lo);
  dim3 mgrid(NPIX / 64, CDIM / 64, BATCH);
  if (KS == 4) {
    attn_kernel<4><<<dim3(64 * BATCH * 4), 256, 0, stream>>>(qt_hi, qt_lo, kt_hi, kt_lo,
                                                             v_hi, v_lo, opart, mlbuf);
    combine_kernel<4><<<mgrid, 256, 0, stream>>>(opart, mlbuf, ao);
  } else {
    attn_kernel<2><<<dim3(64 * BATCH * 2), 256, 0, stream>>>(qt_hi, qt_lo, kt_hi, kt_lo,
                                                             v_hi, v_lo, opart, mlbuf);
    combine_kernel<2><<<mgrid, 256, 0, stream>>>(opart, mlbuf, ao);
  }
  conv1x1_kernel<0><<<cgrid, 256, 0, stream>>>(wp, bp, ao, x, out, nullptr, nullptr);
}